// Round 2
// baseline (1064.921 us; speedup 1.0000x reference)
//
#include <hip/hip_runtime.h>
#include <math.h>

typedef __bf16 bf16_t;
typedef __bf16 bf16x4 __attribute__((ext_vector_type(4)));
typedef __bf16 bf16x8 __attribute__((ext_vector_type(8)));
typedef _Float16 f16x4 __attribute__((ext_vector_type(4)));
typedef _Float16 f16x8 __attribute__((ext_vector_type(8)));
typedef float f32x4 __attribute__((ext_vector_type(4)));

// ---------- helpers ----------

__device__ __forceinline__ bf16_t to_bf16_rne(float x, float& rep) {
    unsigned u = __builtin_bit_cast(unsigned, x);
    unsigned r = u + 0x7fffu + ((u >> 16) & 1u);
    unsigned short h = (unsigned short)(r >> 16);
    rep = __builtin_bit_cast(float, ((unsigned)h) << 16);
    return __builtin_bit_cast(bf16_t, h);
}

__device__ __forceinline__ void g2l16(const void* g, void* l) {
    __builtin_amdgcn_global_load_lds(
        (const __attribute__((address_space(1))) unsigned int*)g,
        (__attribute__((address_space(3))) unsigned int*)l, 16, 0, 0);
}

// stage a 128x32 tile (2-byte elements), row-major source with leading dim ld
template <typename T>
__device__ __forceinline__ void stage128x32(const T* __restrict__ g, int ld, T* lds,
                                            int wid, int lane) {
#pragma unroll
    for (int i = 0; i < 2; ++i) {
        int c = i * 256 + wid * 64 + lane;                 // 16B chunk index, 512 total
        const T* src = g + (long long)(c >> 2) * ld + ((c & 3) << 3);
        T* dst = lds + (size_t)(i * 256 + wid * 64) * 8;   // wave-uniform base
        g2l16(src, dst);
    }
}

// ---------- elementwise prep kernels ----------

__global__ __launch_bounds__(256) void split_bf16_k(const float* __restrict__ in,
                                                    bf16_t* __restrict__ hi,
                                                    bf16_t* __restrict__ lo,
                                                    long long n4) {
    long long i = (long long)blockIdx.x * 256 + threadIdx.x;
    if (i >= n4) return;
    f32x4 v = ((const f32x4*)in)[i];
    bf16x4 hv, lv;
#pragma unroll
    for (int j = 0; j < 4; ++j) {
        float rep;
        hv[j] = to_bf16_rne(v[j], rep);
        float res = v[j] - rep;
        float rep2;
        lv[j] = to_bf16_rne(res, rep2);
    }
    ((bf16x4*)hi)[i] = hv;
    ((bf16x4*)lo)[i] = lv;
}

__global__ __launch_bounds__(256) void cast_f16_k(const float* __restrict__ in,
                                                  _Float16* __restrict__ o, long long n4) {
    long long i = (long long)blockIdx.x * 256 + threadIdx.x;
    if (i >= n4) return;
    f32x4 v = ((const f32x4*)in)[i];
    f16x4 h;
#pragma unroll
    for (int j = 0; j < 4; ++j) h[j] = (_Float16)v[j];
    ((f16x4*)o)[i] = h;
}

// ctx chunk [G][1024][1024] f32 -> ctxT [G][1024(d)][1024(k)] f16
__global__ __launch_bounds__(256) void transpose_ctx_k(const float* __restrict__ ctx,
                                                       _Float16* __restrict__ ctxT) {
    __shared__ _Float16 t[32][34];
    int b = blockIdx.z;
    int k0 = blockIdx.x * 32, d0 = blockIdx.y * 32;
    const float* src = ctx + ((long long)b * 1024 + k0) * 1024 + d0;
#pragma unroll
    for (int i = 0; i < 4; ++i) {
        int y = threadIdx.y + i * 8;
        t[y][threadIdx.x] = (_Float16)src[(long long)y * 1024 + threadIdx.x];
    }
    __syncthreads();
    _Float16* dst = ctxT + ((long long)b * 1024 + d0) * 1024 + k0;
#pragma unroll
    for (int i = 0; i < 4; ++i) {
        int y = threadIdx.y + i * 8;
        dst[(long long)y * 1024 + threadIdx.x] = t[threadIdx.x][y];
    }
}

// per-row masked softmax: w_k = m_k*exp(s_k - max)/sum  (fp32 in, f16 out)
__global__ __launch_bounds__(256) void masked_softmax_k(const float* __restrict__ s,
                                                        const int* __restrict__ m,
                                                        _Float16* __restrict__ w) {
    long long row = blockIdx.x;
    const float* sr = s + row * 1024;
    const int* mr = m + row * 1024;
    _Float16* wr_ = w + row * 1024;
    int t = threadIdx.x;
    int lane = t & 63, wid = t >> 6;
    float v[4];
    int mk[4];
    float mx = -3.0e38f;
#pragma unroll
    for (int i = 0; i < 4; ++i) {
        int idx = t + i * 256;
        v[i] = sr[idx];
        mk[i] = mr[idx];
        if (mk[i]) mx = fmaxf(mx, v[i]);
    }
#pragma unroll
    for (int off = 32; off; off >>= 1) mx = fmaxf(mx, __shfl_xor(mx, off));
    __shared__ float rm[4], rs[4];
    if (!lane) rm[wid] = mx;
    __syncthreads();
    mx = fmaxf(fmaxf(rm[0], rm[1]), fmaxf(rm[2], rm[3]));
    float sum = 0.f;
#pragma unroll
    for (int i = 0; i < 4; ++i) {
        float e = mk[i] ? expf(v[i] - mx) : 0.f;
        v[i] = e;
        sum += e;
    }
#pragma unroll
    for (int off = 32; off; off >>= 1) sum += __shfl_xor(sum, off);
    if (!lane) rs[wid] = sum;
    __syncthreads();
    sum = rs[0] + rs[1] + rs[2] + rs[3];
    float inv = sum > 0.f ? 1.0f / sum : 0.f;  // all-masked row -> zeros (matches ref limit)
#pragma unroll
    for (int i = 0; i < 4; ++i) wr_[t + i * 256] = (_Float16)(v[i] * inv);
}

// ---------- bf16x3 GEMM: C = Ah*Bh^T + Ah*Bl^T + Al*Bh^T ----------
// A: [M x K], B: [N x K]; both row-major, K contiguous (NT).
// EPI 0: write fp32 scores (ld N, + z*sC)
// EPI 1: write q: Qh/Ql bf16 (ld 1024) and f16 Cq (ld 1024)
template <int EPI>
__global__ __launch_bounds__(256) void gemm_x3(
    const bf16_t* __restrict__ Ah, const bf16_t* __restrict__ Al,
    const bf16_t* __restrict__ Bh, const bf16_t* __restrict__ Bl,
    int K, int N, long long sA, long long sB, long long sC,
    float* __restrict__ Cs, bf16_t* __restrict__ Qh, bf16_t* __restrict__ Ql,
    _Float16* __restrict__ Cq) {
    __shared__ bf16_t lAh[128 * 32], lAl[128 * 32], lBh[128 * 32], lBl[128 * 32];
    int tid = threadIdx.x, lane = tid & 63, wid = tid >> 6;
    int wr = wid >> 1, wc = wid & 1;
    long long zA = (long long)blockIdx.z * sA;
    long long zB = (long long)blockIdx.z * sB;
    long long zC = (long long)blockIdx.z * sC;
    int brow = blockIdx.x * 128, bcol = blockIdx.y * 128;
    const bf16_t* pAh = Ah + zA + (long long)brow * K;
    const bf16_t* pAl = Al + zA + (long long)brow * K;
    const bf16_t* pBh = Bh + zB + (long long)bcol * K;
    const bf16_t* pBl = Bl + zB + (long long)bcol * K;
    f32x4 acc[4][4] = {};
    int arow = wr * 64 + (lane & 15);
    int brw = wc * 64 + (lane & 15);
    int kg = (lane >> 4) * 8;
    for (int kt = 0; kt < K; kt += 32) {
        __syncthreads();
        stage128x32(pAh + kt, K, lAh, wid, lane);
        stage128x32(pAl + kt, K, lAl, wid, lane);
        stage128x32(pBh + kt, K, lBh, wid, lane);
        stage128x32(pBl + kt, K, lBl, wid, lane);
        __syncthreads();
        bf16x8 ah[4], al[4], bh[4], bl[4];
#pragma unroll
        for (int mm = 0; mm < 4; ++mm) {
            ah[mm] = *(const bf16x8*)&lAh[(arow + mm * 16) * 32 + kg];
            al[mm] = *(const bf16x8*)&lAl[(arow + mm * 16) * 32 + kg];
        }
#pragma unroll
        for (int nn = 0; nn < 4; ++nn) {
            bh[nn] = *(const bf16x8*)&lBh[(brw + nn * 16) * 32 + kg];
            bl[nn] = *(const bf16x8*)&lBl[(brw + nn * 16) * 32 + kg];
        }
#pragma unroll
        for (int mm = 0; mm < 4; ++mm)
#pragma unroll
            for (int nn = 0; nn < 4; ++nn) {
                acc[mm][nn] = __builtin_amdgcn_mfma_f32_16x16x32_bf16(ah[mm], bh[nn], acc[mm][nn], 0, 0, 0);
                acc[mm][nn] = __builtin_amdgcn_mfma_f32_16x16x32_bf16(ah[mm], bl[nn], acc[mm][nn], 0, 0, 0);
                acc[mm][nn] = __builtin_amdgcn_mfma_f32_16x16x32_bf16(al[mm], bh[nn], acc[mm][nn], 0, 0, 0);
            }
    }
    int r0 = brow + wr * 64 + ((lane >> 4) << 2);
    int c0 = bcol + wc * 64 + (lane & 15);
#pragma unroll
    for (int mm = 0; mm < 4; ++mm)
#pragma unroll
        for (int nn = 0; nn < 4; ++nn)
#pragma unroll
            for (int j = 0; j < 4; ++j) {
                int r = r0 + mm * 16 + j;
                int c = c0 + nn * 16;
                float v = acc[mm][nn][j];
                if (EPI == 0) {
                    Cs[zC + (long long)r * N + c] = v;
                } else {
                    float rep;
                    bf16_t hb = to_bf16_rne(v, rep);
                    float res = v - rep;
                    float rep2;
                    bf16_t lb = to_bf16_rne(res, rep2);
                    long long off = (long long)r * 1024 + c;
                    Qh[off] = hb;
                    Ql[off] = lb;
                    Cq[off] = (_Float16)v;
                }
            }
}

// ---------- f16 GEMM (mix): C[l][d] = sum_k A[l][k] * B[d][k], f16 out ld 1024 ----------
__global__ __launch_bounds__(256) void gemm_mix(
    const _Float16* __restrict__ A, const _Float16* __restrict__ B,
    long long sA, long long sB, long long sC, _Float16* __restrict__ C) {
    __shared__ _Float16 lA[128 * 32], lB[128 * 32];
    int tid = threadIdx.x, lane = tid & 63, wid = tid >> 6;
    int wr = wid >> 1, wc = wid & 1;
    long long zA = (long long)blockIdx.z * sA;
    long long zB = (long long)blockIdx.z * sB;
    long long zC = (long long)blockIdx.z * sC;
    int brow = blockIdx.x * 128, bcol = blockIdx.y * 128;
    const _Float16* pA = A + zA + (long long)brow * 1024;
    const _Float16* pB = B + zB + (long long)bcol * 1024;
    f32x4 acc[4][4] = {};
    int arow = wr * 64 + (lane & 15);
    int brw = wc * 64 + (lane & 15);
    int kg = (lane >> 4) * 8;
    for (int kt = 0; kt < 1024; kt += 32) {
        __syncthreads();
        stage128x32(pA + kt, 1024, lA, wid, lane);
        stage128x32(pB + kt, 1024, lB, wid, lane);
        __syncthreads();
        f16x8 af[4], bf[4];
#pragma unroll
        for (int mm = 0; mm < 4; ++mm) af[mm] = *(const f16x8*)&lA[(arow + mm * 16) * 32 + kg];
#pragma unroll
        for (int nn = 0; nn < 4; ++nn) bf[nn] = *(const f16x8*)&lB[(brw + nn * 16) * 32 + kg];
#pragma unroll
        for (int mm = 0; mm < 4; ++mm)
#pragma unroll
            for (int nn = 0; nn < 4; ++nn)
                acc[mm][nn] = __builtin_amdgcn_mfma_f32_16x16x32_f16(af[mm], bf[nn], acc[mm][nn], 0, 0, 0);
    }
    int r0 = brow + wr * 64 + ((lane >> 4) << 2);
    int c0 = bcol + wc * 64 + (lane & 15);
#pragma unroll
    for (int mm = 0; mm < 4; ++mm)
#pragma unroll
        for (int nn = 0; nn < 4; ++nn)
#pragma unroll
            for (int j = 0; j < 4; ++j)
                C[zC + (long long)(r0 + mm * 16 + j) * 1024 + (c0 + nn * 16)] = (_Float16)acc[mm][nn][j];
}

// ---------- out GEMM: out = tanh(A1*B[:, :1024]^T + A2*B[:, 1024:]^T), K=2048 ----------
// A1 = mix [M x 1024] f16, A2 = q [M x 1024] f16, B = Wout [1024 x 2048] f16 row-major.
__global__ __launch_bounds__(256) void gemm_out(
    const _Float16* __restrict__ A1, const _Float16* __restrict__ A2,
    const _Float16* __restrict__ B, float* __restrict__ C) {
    __shared__ _Float16 lA[128 * 32], lB[128 * 32];
    int tid = threadIdx.x, lane = tid & 63, wid = tid >> 6;
    int wr = wid >> 1, wc = wid & 1;
    int brow = blockIdx.x * 128, bcol = blockIdx.y * 128;
    const _Float16* pA1 = A1 + (long long)brow * 1024;
    const _Float16* pA2 = A2 + (long long)brow * 1024;
    const _Float16* pB = B + (long long)bcol * 2048;
    f32x4 acc[4][4] = {};
    int arow = wr * 64 + (lane & 15);
    int brw = wc * 64 + (lane & 15);
    int kg = (lane >> 4) * 8;
    for (int kt = 0; kt < 2048; kt += 32) {
        __syncthreads();
        if (kt < 1024)
            stage128x32(pA1 + kt, 1024, lA, wid, lane);
        else
            stage128x32(pA2 + (kt - 1024), 1024, lA, wid, lane);
        stage128x32(pB + kt, 2048, lB, wid, lane);
        __syncthreads();
        f16x8 af[4], bf[4];
#pragma unroll
        for (int mm = 0; mm < 4; ++mm) af[mm] = *(const f16x8*)&lA[(arow + mm * 16) * 32 + kg];
#pragma unroll
        for (int nn = 0; nn < 4; ++nn) bf[nn] = *(const f16x8*)&lB[(brw + nn * 16) * 32 + kg];
#pragma unroll
        for (int mm = 0; mm < 4; ++mm)
#pragma unroll
            for (int nn = 0; nn < 4; ++nn)
                acc[mm][nn] = __builtin_amdgcn_mfma_f32_16x16x32_f16(af[mm], bf[nn], acc[mm][nn], 0, 0, 0);
    }
    int r0 = brow + wr * 64 + ((lane >> 4) << 2);
    int c0 = bcol + wc * 64 + (lane & 15);
#pragma unroll
    for (int mm = 0; mm < 4; ++mm)
#pragma unroll
        for (int nn = 0; nn < 4; ++nn)
#pragma unroll
            for (int j = 0; j < 4; ++j)
                C[(long long)(r0 + mm * 16 + j) * 1024 + (c0 + nn * 16)] = tanhf(acc[mm][nn][j]);
}

// ---------- launch ----------

extern "C" void kernel_launch(void* const* d_in, const int* in_sizes, int n_in,
                              void* d_out, int out_size, void* d_ws, size_t ws_size,
                              hipStream_t stream) {
    const float* query = (const float*)d_in[0];   // [32,1024,1024]
    const float* ctx   = (const float*)d_in[1];   // [32,1024,1024]
    const int*   mask  = (const int*)d_in[2];     // [32768,1024]
    const float* Win   = (const float*)d_in[3];   // [1024,1024]
    const float* Wout  = (const float*)d_in[4];   // [1024,2048]
    float* outp = (float*)d_out;                  // [32,1024,1024]

    const long long MB = 1048576ll;
    // per-chunk footprint: 8 half-precision bufs (2G MB each) + scores f32 (4G MB) = 20G MB,
    // plus 8 MB weights. Pick largest G that fits ws_size.
    int G = 1;
    if ((long long)ws_size >= 648 * MB) G = 32;
    else if ((long long)ws_size >= 328 * MB) G = 16;
    else if ((long long)ws_size >= 168 * MB) G = 8;
    else if ((long long)ws_size >= 88 * MB) G = 4;
    else if ((long long)ws_size >= 48 * MB) G = 2;

    char* p = (char*)d_ws;
    bf16_t* win_hi = (bf16_t*)p; p += 2 * MB;
    bf16_t* win_lo = (bf16_t*)p; p += 2 * MB;
    _Float16* woutf = (_Float16*)p; p += 4 * MB;
    const long long R = (long long)G * 1024;   // rows per chunk
    const long long b2 = R * 1024 * 2;         // bytes of one half-precision chunk buffer
    bf16_t* q_hi = (bf16_t*)p; p += b2;
    bf16_t* q_lo = (bf16_t*)p; p += b2;
    _Float16* qf = (_Float16*)p; p += b2;
    bf16_t* c_hi = (bf16_t*)p; p += b2;
    bf16_t* c_lo = (bf16_t*)p; p += b2;
    _Float16* ctxT = (_Float16*)p; p += b2;
    _Float16* wf = (_Float16*)p; p += b2;
    _Float16* mixf = (_Float16*)p; p += b2;
    float* scores = (float*)p;                 // 4G MB, aliased with qsrc split below
    bf16_t* qs_hi = (bf16_t*)p;
    bf16_t* qs_lo = (bf16_t*)(p + b2);

    const long long LD = 1048576ll;  // 1024*1024 elements

    // weights prep (once)
    split_bf16_k<<<1024, 256, 0, stream>>>(Win, win_hi, win_lo, 262144ll);
    cast_f16_k<<<2048, 256, 0, stream>>>(Wout, woutf, 524288ll);

    for (int b0 = 0; b0 < 32; b0 += G) {
        const float* qsrc = query + (long long)b0 * LD;
        const float* csrc = ctx + (long long)b0 * LD;
        // split query chunk into scores-aliased region (free before GEMM2)
        split_bf16_k<<<(int)R, 256, 0, stream>>>(qsrc, qs_hi, qs_lo, R * 256);
        // GEMM1: q = query @ Win^T  (bf16x3) -> q_hi/q_lo/qf
        gemm_x3<1><<<dim3(G * 8, 8, 1), 256, 0, stream>>>(
            qs_hi, qs_lo, win_hi, win_lo, 1024, 1024, 0, 0, 0,
            nullptr, q_hi, q_lo, qf);
        // ctx chunk prep
        split_bf16_k<<<(int)R, 256, 0, stream>>>(csrc, c_hi, c_lo, R * 256);
        transpose_ctx_k<<<dim3(32, 32, G), dim3(32, 8, 1), 0, stream>>>(csrc, ctxT);
        // GEMM2: scores = q @ ctx^T (bf16x3)
        gemm_x3<0><<<dim3(8, 8, G), 256, 0, stream>>>(
            q_hi, q_lo, c_hi, c_lo, 1024, 1024, LD, LD, LD,
            scores, nullptr, nullptr, nullptr);
        // softmax
        masked_softmax_k<<<(int)R, 256, 0, stream>>>(scores, mask + (long long)b0 * 1024 * 1024, wf);
        // GEMM3: mix = w @ ctxT^T (f16)
        gemm_mix<<<dim3(8, 8, G), 256, 0, stream>>>(wf, ctxT, LD, LD, LD, mixf);
        // GEMM4: out = tanh(mix @ W1^T + q @ W2^T)
        gemm_out<<<dim3(G * 8, 8, 1), 256, 0, stream>>>(mixf, qf, woutf, outp + (long long)b0 * LD);
    }
}

// Round 3
// 784.372 us; speedup vs baseline: 1.3577x; 1.3577x over previous
//
#include <hip/hip_runtime.h>
#include <math.h>

typedef __bf16 bf16_t;
typedef __bf16 bf16x4 __attribute__((ext_vector_type(4)));
typedef __bf16 bf16x8 __attribute__((ext_vector_type(8)));
typedef _Float16 f16x4 __attribute__((ext_vector_type(4)));
typedef _Float16 f16x8 __attribute__((ext_vector_type(8)));
typedef float f32x4 __attribute__((ext_vector_type(4)));

#define MFMA_BF16 __builtin_amdgcn_mfma_f32_16x16x32_bf16
#define MFMA_F16  __builtin_amdgcn_mfma_f32_16x16x32_f16

// ---------- helpers ----------

__device__ __forceinline__ bf16_t to_bf16_rne(float x, float& rep) {
    unsigned u = __builtin_bit_cast(unsigned, x);
    unsigned r = u + 0x7fffu + ((u >> 16) & 1u);
    unsigned short h = (unsigned short)(r >> 16);
    rep = __builtin_bit_cast(float, ((unsigned)h) << 16);
    return __builtin_bit_cast(bf16_t, h);
}

__device__ __forceinline__ void g2l16(const void* g, void* l) {
    __builtin_amdgcn_global_load_lds(
        (const __attribute__((address_space(1))) unsigned int*)g,
        (__attribute__((address_space(3))) unsigned int*)l, 16, 0, 0);
}

// element offset of logical 16B-chunk (row r in 0..255, chunk j in 0..7) in a
// bank-swizzled [256][8-chunk] tile (rows are 128B). Swizzle: j ^= (r&7) — an
// involution confined to the low-3 chunk bits, applied identically on the
// staging source (pre-swizzled global address) and on every ds_read.
__device__ __forceinline__ int lch(int r, int j) {
    return (r * 8 + (j ^ (r & 7))) * 8;
}

// stage one K-tile: A-tile (256 rows x 128B) + B-tile into buf (linear dest,
// per-lane pre-swizzled global source). 8 global_load_lds per thread.
template <typename T>
__device__ __forceinline__ void stage2(const T* __restrict__ gA, long long ldA,
                                       const T* __restrict__ gB, long long ldB,
                                       T* buf, int tid) {
    int wid = tid >> 6, lane = tid & 63;
#pragma unroll
    for (int i = 0; i < 4; ++i) {
        int cb = i * 512 + wid * 64;
        int c = cb + lane;
        int r = c >> 3, j = (c & 7) ^ (r & 7);
        g2l16(gA + (long long)r * ldA + j * 8, buf + (size_t)cb * 8);
    }
#pragma unroll
    for (int i = 0; i < 4; ++i) {
        int cb = i * 512 + wid * 64;
        int c = cb + lane;
        int r = c >> 3, j = (c & 7) ^ (r & 7);
        g2l16(gB + (long long)r * ldB + j * 8, buf + 16384 + (size_t)cb * 8);
    }
}

// ---------- elementwise prep kernels ----------

// f32 [rows][1024] -> interleaved bf16 hi/lo pairs: row stride 2048, each 32-k
// block stored as [32 hi | 32 lo].
__global__ __launch_bounds__(256) void split_int_k(const float* __restrict__ in,
                                                   bf16_t* __restrict__ out,
                                                   long long n4) {
    long long i = (long long)blockIdx.x * 256 + threadIdx.x;
    if (i >= n4) return;
    f32x4 v = ((const f32x4*)in)[i];
    bf16x4 hv, lv;
#pragma unroll
    for (int j = 0; j < 4; ++j) {
        float rep;
        hv[j] = to_bf16_rne(v[j], rep);
        float res = v[j] - rep;
        float rep2;
        lv[j] = to_bf16_rne(res, rep2);
    }
    long long row = i >> 8;
    int k = (int)(i & 255) * 4;
    long long base = row * 2048 + ((k >> 5) << 6) + (k & 31);
    *(bf16x4*)(out + base) = hv;
    *(bf16x4*)(out + base + 32) = lv;
}

__global__ __launch_bounds__(256) void cast_f16_k(const float* __restrict__ in,
                                                  _Float16* __restrict__ o, long long n4) {
    long long i = (long long)blockIdx.x * 256 + threadIdx.x;
    if (i >= n4) return;
    f32x4 v = ((const f32x4*)in)[i];
    f16x4 h;
#pragma unroll
    for (int j = 0; j < 4; ++j) h[j] = (_Float16)v[j];
    ((f16x4*)o)[i] = h;
}

// ctx chunk [G][1024][1024] f32 -> ctxT [G][1024(d)][1024(k)] f16
__global__ __launch_bounds__(256) void transpose_ctx_k(const float* __restrict__ ctx,
                                                       _Float16* __restrict__ ctxT) {
    __shared__ _Float16 t[32][34];
    int b = blockIdx.z;
    int k0 = blockIdx.x * 32, d0 = blockIdx.y * 32;
    const float* src = ctx + ((long long)b * 1024 + k0) * 1024 + d0;
#pragma unroll
    for (int i = 0; i < 4; ++i) {
        int y = threadIdx.y + i * 8;
        t[y][threadIdx.x] = (_Float16)src[(long long)y * 1024 + threadIdx.x];
    }
    __syncthreads();
    _Float16* dst = ctxT + ((long long)b * 1024 + d0) * 1024 + k0;
#pragma unroll
    for (int i = 0; i < 4; ++i) {
        int y = threadIdx.y + i * 8;
        dst[(long long)y * 1024 + threadIdx.x] = t[threadIdx.x][y];
    }
}

// per-row masked softmax: w_k = m_k*exp(s_k - max)/sum  (fp32 in, f16 out)
__global__ __launch_bounds__(256) void masked_softmax_k(const float* __restrict__ s,
                                                        const int* __restrict__ m,
                                                        _Float16* __restrict__ w) {
    long long row = blockIdx.x;
    const float* sr = s + row * 1024;
    const int* mr = m + row * 1024;
    _Float16* wr_ = w + row * 1024;
    int t = threadIdx.x;
    int lane = t & 63, wid = t >> 6;
    float v[4];
    int mk[4];
    float mx = -3.0e38f;
#pragma unroll
    for (int i = 0; i < 4; ++i) {
        int idx = t + i * 256;
        v[i] = sr[idx];
        mk[i] = mr[idx];
        if (mk[i]) mx = fmaxf(mx, v[i]);
    }
#pragma unroll
    for (int off = 32; off; off >>= 1) mx = fmaxf(mx, __shfl_xor(mx, off));
    __shared__ float rm[4], rs[4];
    if (!lane) rm[wid] = mx;
    __syncthreads();
    mx = fmaxf(fmaxf(rm[0], rm[1]), fmaxf(rm[2], rm[3]));
    float sum = 0.f;
#pragma unroll
    for (int i = 0; i < 4; ++i) {
        float e = mk[i] ? expf(v[i] - mx) : 0.f;
        v[i] = e;
        sum += e;
    }
#pragma unroll
    for (int off = 32; off; off >>= 1) sum += __shfl_xor(sum, off);
    if (!lane) rs[wid] = sum;
    __syncthreads();
    sum = rs[0] + rs[1] + rs[2] + rs[3];
    float inv = sum > 0.f ? 1.0f / sum : 0.f;
#pragma unroll
    for (int i = 0; i < 4; ++i) wr_[t + i * 256] = (_Float16)(v[i] * inv);
}

// ---------- 256x256 deep-pipelined bf16x3 GEMM ----------
// A,B: interleaved hi/lo pair layout, rows of 2048 elements, K=1024 (BK=32).
// C = Ah*Bh^T + Ah*Bl^T + Al*Bh^T. 8 waves (2x4), dbuf LDS 128 KiB,
// counted vmcnt(8), raw barriers, swizzled reads.
// EPI 0: f32 scores (ld 1024, +z*sC). EPI 1: qint interleaved + qf f16.
template <int EPI>
__global__ __launch_bounds__(512, 2) void gemm_x3_256(
    const bf16_t* __restrict__ Aint, const bf16_t* __restrict__ Bint,
    long long sA, long long sB, long long sC, int nbx, int nby,
    float* __restrict__ Cs, bf16_t* __restrict__ Qint, _Float16* __restrict__ Qf) {
    __shared__ bf16_t lds[65536];
    const int NT = 32;
    int tid = threadIdx.x, lane = tid & 63, wid = tid >> 6;
    int wr = wid >> 2, wc = wid & 3;
    int nwg = gridDim.x;
    int bid = blockIdx.x;
    int lid = (bid & 7) * (nwg >> 3) + (bid >> 3);   // XCD-contiguous remap
    int by = lid % nby;
    int t2 = lid / nby;
    int bx = t2 % nbx;
    int z = t2 / nbx;
    const bf16_t* At = Aint + (long long)z * sA + (long long)bx * 256 * 2048;
    const bf16_t* Bt = Bint + (long long)z * sB + (long long)by * 256 * 2048;
    stage2(At, 2048ll, Bt, 2048ll, lds, tid);
    stage2(At + 64, 2048ll, Bt + 64, 2048ll, lds + 32768, tid);
    f32x4 acc[8][4] = {};
    for (int t = 0; t < NT; ++t) {
        bf16_t* buf = lds + (size_t)(t & 1) * 32768;
        bf16_t* bufB = buf + 16384;
        if (t < NT - 1) {
            asm volatile("s_waitcnt vmcnt(8)" ::: "memory");
        } else {
            asm volatile("s_waitcnt vmcnt(0)" ::: "memory");
        }
        __builtin_amdgcn_sched_barrier(0);
        __builtin_amdgcn_s_barrier();
        __builtin_amdgcn_sched_barrier(0);
        bf16x8 bh[4], bl[4];
#pragma unroll
        for (int n = 0; n < 4; ++n) {
            int rB = wc * 64 + n * 16 + (lane & 15);
            bh[n] = *(const bf16x8*)(bufB + lch(rB, lane >> 4));
            bl[n] = *(const bf16x8*)(bufB + lch(rB, 4 + (lane >> 4)));
        }
#pragma unroll
        for (int p = 0; p < 3; ++p) {
            bf16x8 ah[2], al[2];
#pragma unroll
            for (int i = 0; i < 2; ++i) {
                int rA = wr * 128 + (p * 2 + i) * 16 + (lane & 15);
                ah[i] = *(const bf16x8*)(buf + lch(rA, lane >> 4));
                al[i] = *(const bf16x8*)(buf + lch(rA, 4 + (lane >> 4)));
            }
            __builtin_amdgcn_s_setprio(1);
#pragma unroll
            for (int i = 0; i < 2; ++i)
#pragma unroll
                for (int n = 0; n < 4; ++n) {
                    f32x4 a = acc[p * 2 + i][n];
                    a = MFMA_BF16(ah[i], bh[n], a, 0, 0, 0);
                    a = MFMA_BF16(ah[i], bl[n], a, 0, 0, 0);
                    a = MFMA_BF16(al[i], bh[n], a, 0, 0, 0);
                    acc[p * 2 + i][n] = a;
                }
            __builtin_amdgcn_s_setprio(0);
        }
        bf16x8 ah3[2], al3[2];
#pragma unroll
        for (int i = 0; i < 2; ++i) {
            int rA = wr * 128 + (6 + i) * 16 + (lane & 15);
            ah3[i] = *(const bf16x8*)(buf + lch(rA, lane >> 4));
            al3[i] = *(const bf16x8*)(buf + lch(rA, 4 + (lane >> 4)));
        }
        asm volatile("s_waitcnt lgkmcnt(0)" ::: "memory");
        __builtin_amdgcn_sched_barrier(0);
        __builtin_amdgcn_s_barrier();
        __builtin_amdgcn_sched_barrier(0);
        if (t + 2 < NT)
            stage2(At + (long long)(t + 2) * 64, 2048ll, Bt + (long long)(t + 2) * 64,
                   2048ll, buf, tid);
        __builtin_amdgcn_s_setprio(1);
#pragma unroll
        for (int i = 0; i < 2; ++i)
#pragma unroll
            for (int n = 0; n < 4; ++n) {
                f32x4 a = acc[6 + i][n];
                a = MFMA_BF16(ah3[i], bh[n], a, 0, 0, 0);
                a = MFMA_BF16(ah3[i], bl[n], a, 0, 0, 0);
                a = MFMA_BF16(al3[i], bh[n], a, 0, 0, 0);
                acc[6 + i][n] = a;
            }
        __builtin_amdgcn_s_setprio(0);
    }
    int r0 = bx * 256 + wr * 128 + ((lane >> 4) << 2);
    int c0 = by * 256 + wc * 64 + (lane & 15);
#pragma unroll
    for (int m = 0; m < 8; ++m)
#pragma unroll
        for (int n = 0; n < 4; ++n)
#pragma unroll
            for (int j = 0; j < 4; ++j) {
                int r = r0 + m * 16 + j;
                int c = c0 + n * 16;
                float v = acc[m][n][j];
                if (EPI == 0) {
                    Cs[(long long)z * sC + (long long)r * 1024 + c] = v;
                } else {
                    float rep;
                    bf16_t hb = to_bf16_rne(v, rep);
                    float res = v - rep;
                    float rep2;
                    bf16_t lb = to_bf16_rne(res, rep2);
                    long long rb = (long long)r * 2048 + ((c >> 5) << 6) + (c & 31);
                    Qint[rb] = hb;
                    Qint[rb + 32] = lb;
                    Qf[(long long)r * 1024 + c] = (_Float16)v;
                }
            }
}

// ---------- 256x256 deep-pipelined f16 GEMM ----------
// A rows K-contig (ldA), optional A-source switch at tile swt (for the K=2048
// concat GEMM). B rows K-contig (ldB). BK=64, NT tiles.
// EPI 0: f16 out (ld 1024, +z*sC). EPI 1: f32 tanh out (ld 1024).
template <int EPI>
__global__ __launch_bounds__(512, 2) void gemm_f16_256(
    const _Float16* __restrict__ A1, const _Float16* __restrict__ A2,
    const _Float16* __restrict__ B,
    long long ldA, long long ldB, long long sA, long long sB, long long sC,
    int NT, int swt, int nbx, int nby,
    _Float16* __restrict__ Cm, float* __restrict__ Co) {
    __shared__ _Float16 lds[65536];
    int tid = threadIdx.x, lane = tid & 63, wid = tid >> 6;
    int wr = wid >> 2, wc = wid & 3;
    int nwg = gridDim.x;
    int bid = blockIdx.x;
    int lid = (bid & 7) * (nwg >> 3) + (bid >> 3);
    int by = lid % nby;
    int t2 = lid / nby;
    int bx = t2 % nbx;
    int z = t2 / nbx;
    const _Float16* A1t = A1 + (long long)z * sA + (long long)bx * 256 * ldA;
    const _Float16* A2t = A2 + (long long)bx * 256 * ldA;
    const _Float16* Bt = B + (long long)z * sB + (long long)by * 256 * ldB;
    stage2((0 < swt) ? A1t : A2t, ldA, Bt, ldB, lds, tid);
    stage2((1 < swt) ? A1t + 64 : A2t + (long long)(1 - swt) * 64, ldA, Bt + 64, ldB,
           lds + 32768, tid);
    f32x4 acc[8][4] = {};
    for (int t = 0; t < NT; ++t) {
        _Float16* buf = lds + (size_t)(t & 1) * 32768;
        _Float16* bufB = buf + 16384;
        if (t < NT - 1) {
            asm volatile("s_waitcnt vmcnt(8)" ::: "memory");
        } else {
            asm volatile("s_waitcnt vmcnt(0)" ::: "memory");
        }
        __builtin_amdgcn_sched_barrier(0);
        __builtin_amdgcn_s_barrier();
        __builtin_amdgcn_sched_barrier(0);
        f16x8 bfr[4][2];
#pragma unroll
        for (int n = 0; n < 4; ++n)
#pragma unroll
            for (int ks = 0; ks < 2; ++ks) {
                int rB = wc * 64 + n * 16 + (lane & 15);
                bfr[n][ks] = *(const f16x8*)(bufB + lch(rB, ks * 4 + (lane >> 4)));
            }
#pragma unroll
        for (int p = 0; p < 3; ++p) {
            f16x8 a[2][2];
#pragma unroll
            for (int i = 0; i < 2; ++i)
#pragma unroll
                for (int ks = 0; ks < 2; ++ks) {
                    int rA = wr * 128 + (p * 2 + i) * 16 + (lane & 15);
                    a[i][ks] = *(const f16x8*)(buf + lch(rA, ks * 4 + (lane >> 4)));
                }
            __builtin_amdgcn_s_setprio(1);
#pragma unroll
            for (int i = 0; i < 2; ++i)
#pragma unroll
                for (int n = 0; n < 4; ++n) {
                    f32x4 v = acc[p * 2 + i][n];
                    v = MFMA_F16(a[i][0], bfr[n][0], v, 0, 0, 0);
                    v = MFMA_F16(a[i][1], bfr[n][1], v, 0, 0, 0);
                    acc[p * 2 + i][n] = v;
                }
            __builtin_amdgcn_s_setprio(0);
        }
        f16x8 a3[2][2];
#pragma unroll
        for (int i = 0; i < 2; ++i)
#pragma unroll
            for (int ks = 0; ks < 2; ++ks) {
                int rA = wr * 128 + (6 + i) * 16 + (lane & 15);
                a3[i][ks] = *(const f16x8*)(buf + lch(rA, ks * 4 + (lane >> 4)));
            }
        asm volatile("s_waitcnt lgkmcnt(0)" ::: "memory");
        __builtin_amdgcn_sched_barrier(0);
        __builtin_amdgcn_s_barrier();
        __builtin_amdgcn_sched_barrier(0);
        if (t + 2 < NT) {
            int tt = t + 2;
            const _Float16* gA =
                (tt < swt) ? A1t + (long long)tt * 64 : A2t + (long long)(tt - swt) * 64;
            stage2(gA, ldA, Bt + (long long)tt * 64, ldB, buf, tid);
        }
        __builtin_amdgcn_s_setprio(1);
#pragma unroll
        for (int i = 0; i < 2; ++i)
#pragma unroll
            for (int n = 0; n < 4; ++n) {
                f32x4 v = acc[6 + i][n];
                v = MFMA_F16(a3[i][0], bfr[n][0], v, 0, 0, 0);
                v = MFMA_F16(a3[i][1], bfr[n][1], v, 0, 0, 0);
                acc[6 + i][n] = v;
            }
        __builtin_amdgcn_s_setprio(0);
    }
    int r0 = bx * 256 + wr * 128 + ((lane >> 4) << 2);
    int c0 = by * 256 + wc * 64 + (lane & 15);
#pragma unroll
    for (int m = 0; m < 8; ++m)
#pragma unroll
        for (int n = 0; n < 4; ++n)
#pragma unroll
            for (int j = 0; j < 4; ++j) {
                int r = r0 + m * 16 + j;
                int c = c0 + n * 16;
                float v = acc[m][n][j];
                if (EPI == 0) {
                    Cm[(long long)z * sC + (long long)r * 1024 + c] = (_Float16)v;
                } else {
                    Co[(long long)r * 1024 + c] = tanhf(v);
                }
            }
}

// ---------- launch ----------

extern "C" void kernel_launch(void* const* d_in, const int* in_sizes, int n_in,
                              void* d_out, int out_size, void* d_ws, size_t ws_size,
                              hipStream_t stream) {
    const float* query = (const float*)d_in[0];
    const float* ctx = (const float*)d_in[1];
    const int* mask = (const int*)d_in[2];
    const float* Win = (const float*)d_in[3];
    const float* Wout = (const float*)d_in[4];
    float* outp = (float*)d_out;

    const long long MB = 1048576ll;
    int G = 1;
    if ((long long)ws_size >= 648 * MB) G = 32;
    else if ((long long)ws_size >= 328 * MB) G = 16;
    else if ((long long)ws_size >= 168 * MB) G = 8;
    else if ((long long)ws_size >= 88 * MB) G = 4;
    else if ((long long)ws_size >= 48 * MB) G = 2;

    char* p = (char*)d_ws;
    bf16_t* win_int = (bf16_t*)p; p += 4 * MB;     // [1024][2048] interleaved
    _Float16* woutf = (_Float16*)p; p += 4 * MB;   // [1024][2048]
    const long long R = (long long)G * 1024;
    bf16_t* qint = (bf16_t*)p; p += 4 * G * MB;    // [R][2048] interleaved
    _Float16* qf = (_Float16*)p; p += 2 * G * MB;  // [R][1024]
    bf16_t* ctx_int = (bf16_t*)p; p += 4 * G * MB; // [R][2048] interleaved
    _Float16* ctxT = (_Float16*)p; p += 2 * G * MB;
    _Float16* wf = (_Float16*)p; p += 2 * G * MB;
    _Float16* mixf = (_Float16*)p; p += 2 * G * MB;
    bf16_t* qs_int = (bf16_t*)p;                   // 4G MB (dead before scores)
    float* scores = (float*)p;                     // 4G MB, same region

    const long long LD = 1048576ll;

    split_int_k<<<1024, 256, 0, stream>>>(Win, win_int, 262144ll);
    cast_f16_k<<<2048, 256, 0, stream>>>(Wout, woutf, 524288ll);

    for (int b0 = 0; b0 < 32; b0 += G) {
        const float* qsrc = query + (long long)b0 * LD;
        const float* csrc = ctx + (long long)b0 * LD;
        split_int_k<<<(int)R, 256, 0, stream>>>(qsrc, qs_int, R * 256);
        // GEMM1: q = query @ Win^T (bf16x3) -> qint (interleaved) + qf (f16)
        gemm_x3_256<1><<<16 * G, 512, 0, stream>>>(
            qs_int, win_int, 0, 0, 0, 4 * G, 4, nullptr, qint, qf);
        split_int_k<<<(int)R, 256, 0, stream>>>(csrc, ctx_int, R * 256);
        transpose_ctx_k<<<dim3(32, 32, G), dim3(32, 8, 1), 0, stream>>>(csrc, ctxT);
        // GEMM2: scores = q @ ctx^T (bf16x3)
        gemm_x3_256<0><<<16 * G, 512, 0, stream>>>(
            qint, ctx_int, 2097152ll, 2097152ll, 1048576ll, 4, 4,
            scores, nullptr, nullptr);
        masked_softmax_k<<<(int)R, 256, 0, stream>>>(
            scores, mask + (long long)b0 * 1024 * 1024, wf);
        // GEMM3: mix = w @ ctxT^T (f16)
        gemm_f16_256<0><<<16 * G, 512, 0, stream>>>(
            wf, wf, ctxT, 1024ll, 1024ll, 1048576ll, 1048576ll, 1048576ll,
            16, 1 << 20, 4, 4, mixf, nullptr);
        // GEMM4: out = tanh(mix @ W1^T + q @ W2^T), K=2048, A-switch at tile 16
        gemm_f16_256<1><<<16 * G, 512, 0, stream>>>(
            mixf, qf, woutf, 1024ll, 2048ll, 0, 0, 0,
            32, 16, 4 * G, 4, nullptr, outp + (long long)b0 * LD);
    }
}